// Round 8
// baseline (2588.018 us; speedup 1.0000x reference)
//
#include <hip/hip_runtime.h>
#include <math.h>

typedef unsigned short u16;
typedef long long ll;
typedef __attribute__((ext_vector_type(8))) short short8;
typedef __attribute__((ext_vector_type(4))) short short4v;
typedef __attribute__((ext_vector_type(4))) float f32x4;

// Problem constants
#define TBINS 8
#define BATCH 4
#define CIN 3
#define WIMG 128
#define PC 48
#define NVOX 8192
#define ID 435
#define IDP 448      // ceil32(435)
#define LD 512
#define INNER 600
#define INNERP 608   // ceil32(600)
#define FFD 2048
#define NL 128
#define OC 64
#define DEPTH 5
#define HEADS 8
#define DH 75
#define DHP 96       // ceil32(75)
#define BK 32
#define NCH 16       // flash chunks over 8192 vox
#define FCH 512      // vox per chunk
#define FKT 64       // flash k-tile
#define KVLD 1536    // kv projection padded width (2*8*96)
#define QLD 768      // q padded width (8*96)
#define QKVLD 2304   // self qkv padded width (3*8*96)

static __device__ __forceinline__ u16 f2bf(float f) {
    unsigned x = __float_as_uint(f);
    unsigned r = (x + 0x7fffu + ((x >> 16) & 1u)) >> 16;
    return (u16)r;
}
static __device__ __forceinline__ float bf2f(u16 v) {
    return __uint_as_float(((unsigned)v) << 16);
}
static __device__ __forceinline__ void gload_lds16(const u16* g, u16* l) {
    __builtin_amdgcn_global_load_lds(
        (const __attribute__((address_space(1))) unsigned int*)g,
        (__attribute__((address_space(3))) unsigned int*)l, 16, 0, 0);
}

// ---------------------------------------------------------------------------
__global__ __launch_bounds__(256) void mask_kernel(const float* __restrict__ input,
                                                   unsigned char* __restrict__ mask) {
    int idx = blockIdx.x * 256 + threadIdx.x;
    if (idx >= BATCH * NVOX) return;
    int b = idx >> 13, i = idx & (NVOX - 1);
    int tt = i & 7, wx = (i >> 3) & 31, hy = i >> 8;
    float mx = -3.4e38f;
    for (int ch = 0; ch < PC; ++ch) {
        int py = ch / 12, px = (ch / 3) & 3, cc = ch % 3;
        float v = input[((size_t)((tt * BATCH + b) * CIN + cc) << 14) +
                        (hy * 4 + py) * WIMG + (wx * 4 + px)];
        mx = fmaxf(mx, v);
    }
    mask[idx] = (fabsf(mx) > 0.3f) ? 1 : 0;
}

__global__ __launch_bounds__(64) void compact_kernel(const unsigned char* __restrict__ mask,
                                                     int* __restrict__ perm,
                                                     int* __restrict__ Kc) {
    int b = blockIdx.x, lane = threadIdx.x;
    int offs = 0;
    for (int c = 0; c < NVOX / 64; ++c) {
        int i = c * 64 + lane;
        int m = mask[(b << 13) + i];
        unsigned long long bal = __ballot(m != 0);
        int excl = __popcll(bal & ((1ull << lane) - 1ull));
        if (m) perm[(b << 13) + offs + excl] = i;
        offs += __popcll(bal);
    }
    if (lane == 0) Kc[b] = offs;
}

// build normalized data rows (bf16, ld IDP) for ALL batches, one launch
__global__ __launch_bounds__(256) void build_all(const float* __restrict__ input,
                                                 const int* __restrict__ perm,
                                                 const int* __restrict__ Kc,
                                                 u16* __restrict__ normed) {
    int blk = blockIdx.x;             // b*8192 + r
    int b = blk >> 13, r = blk & (NVOX - 1);
    int tid = threadIdx.x;
    u16* out = normed + (size_t)blk * IDP;
    int Kb = Kc[b];
    if (r >= Kb) {
        for (int e = tid; e < IDP; e += 256) out[e] = 0;
        return;
    }
    __shared__ float row[IDP];
    __shared__ float red[256];
    int i = perm[(b << 13) + r];
    int tt = i & 7, wx = (i >> 3) & 31, hy = i >> 8;
    float pos0 = 2.f * hy / 32.f - 1.f;
    float pos1 = 2.f * wx / 32.f - 1.f;
    float pos2 = 2.f * tt / 8.f - 1.f;
    for (int e = tid; e < IDP; e += 256) {
        float v = 0.f;
        if (e < PC) {
            int py = e / 12, px = (e / 3) & 3, cc = e % 3;
            v = input[((size_t)((tt * BATCH + b) * CIN + cc) << 14) +
                      (hy * 4 + py) * WIMG + (wx * 4 + px)];
        } else if (e < ID) {
            int e2 = e - PC;
            int dim = e2 / 129, rem = e2 - dim * 129;
            float pp = (dim == 0) ? pos0 : (dim == 1 ? pos1 : pos2);
            if (rem < 64)       v = sinf(ldexpf(pp, -rem));
            else if (rem < 128) v = cosf(ldexpf(pp, -(rem - 64)));
            else                v = pp;
        }
        row[e] = v;
    }
    __syncthreads();
    float ss = 0.f;
    for (int e = tid; e < ID; e += 256) ss += row[e] * row[e];
    red[tid] = ss; __syncthreads();
    for (int s = 128; s > 0; s >>= 1) { if (tid < s) red[tid] += red[tid + s]; __syncthreads(); }
    float scale = 1.f / fmaxf(sqrtf(red[0]), 1e-5f);
    for (int e = tid; e < IDP; e += 256) out[e] = f2bf(row[e] * scale);
}

__global__ __launch_bounds__(256) void lat_init(const float* __restrict__ latents,
                                                const float* __restrict__ pos_emb,
                                                float* __restrict__ lat) {
    int idx = blockIdx.x * 256 + threadIdx.x;
    if (idx >= BATCH * NL * LD) return;
    int rem = idx & (NL * LD - 1);
    lat[idx] = latents[rem] + pos_emb[rem];
}

__global__ __launch_bounds__(256) void scale_norm_bf(const float* __restrict__ x,
                                                     u16* __restrict__ o,
                                                     const float* __restrict__ g, int gi,
                                                     int cols) {
    int rowi = blockIdx.x, tid = threadIdx.x;
    const float* xr = x + (size_t)rowi * cols;
    u16* orow = o + (size_t)rowi * cols;
    __shared__ float red[256];
    float ss = 0.f;
    for (int c = tid; c < cols; c += 256) { float v = xr[c]; ss += v * v; }
    red[tid] = ss; __syncthreads();
    for (int s = 128; s > 0; s >>= 1) { if (tid < s) red[tid] += red[tid + s]; __syncthreads(); }
    float scale = g[gi] / fmaxf(sqrtf(red[0]), 1e-5f);
    for (int c = tid; c < cols; c += 256) orow[c] = f2bf(xr[c] * scale);
}

__global__ __launch_bounds__(256) void fill_kernel(float* __restrict__ p, long long n, float v) {
    long long idx = (long long)blockIdx.x * 256 + threadIdx.x;
    if (idx < n) p[idx] = v;
}

__global__ __launch_bounds__(256) void conv_bf(const float* __restrict__ src, u16* __restrict__ dst, int n) {
    int idx = blockIdx.x * 256 + threadIdx.x;
    if (idx < n) dst[idx] = f2bf(src[idx]);
}

// batched transpose: fp32 (R x C) -> bf16 (cp(c) x Rp) per job; one launch
// flag 0: cp=c. flag 1: cp=(c/75)*96+c%75. flag 2: cp=(c/600)*768+((c%600)/75)*96+(c%600)%75.
struct TJobs {
    const float* src[11];
    u16* dst[11];
    int R[11], C[11], Rp[11], flag[11];
    int tstart[12];
    int njobs;
};
__global__ __launch_bounds__(256) void transpose_multi(TJobs J) {
    int bx = blockIdx.x;
    int j = 0;
    while (j + 1 < J.njobs && bx >= J.tstart[j + 1]) ++j;
    int lt = bx - J.tstart[j];
    int tilesX = J.Rp[j] >> 5;
    int tx = lt % tilesX, ty = lt / tilesX;
    const float* src = J.src[j];
    u16* dst = J.dst[j];
    int R = J.R[j], C = J.C[j], Rp = J.Rp[j], fl = J.flag[j];
    __shared__ float t[32][33];
    int bx0 = tx * 32, by0 = ty * 32;
    int ttx = threadIdx.x & 31, tty = threadIdx.x >> 5;
#pragma unroll
    for (int p = 0; p < 4; ++p) {
        int r = bx0 + tty + p * 8, c = by0 + ttx;
        t[tty + p * 8][ttx] = (r < R && c < C) ? src[(size_t)r * C + c] : 0.f;
    }
    __syncthreads();
#pragma unroll
    for (int p = 0; p < 4; ++p) {
        int c = by0 + tty + p * 8, r = bx0 + ttx;
        if (c < C && r < Rp) {
            int cp = c;
            if (fl == 1)      cp = (c / 75) * 96 + c % 75;
            else if (fl == 2) { int sec = c / 600, rem = c - sec * 600;
                                cp = sec * 768 + (rem / 75) * 96 + rem % 75; }
            dst[(size_t)cp * Rp + r] = f2bf(t[ttx][tty + p * 8]);
        }
    }
}

// vs_t (bh,DH,NL) from qkvs (512 x QKVLD) V section
__global__ __launch_bounds__(256) void pack_vt_self(const u16* __restrict__ qkvs, u16* __restrict__ vt) {
    int idx = blockIdx.x * 256 + threadIdx.x;
    if (idx >= BATCH * HEADS * DH * NL) return;
    int l = idx & (NL - 1);
    int dd = (idx >> 7) % DH;
    int bh = idx / (DH * NL);
    int b = bh >> 3, h = bh & 7;
    vt[idx] = qkvs[(size_t)(b * NL + l) * QKVLD + 2 * QLD + h * DHP + dd];
}

// masked softmax on bf16 in place (self-attn scores, cols=128)
__global__ __launch_bounds__(256) void softmax_u16(u16* __restrict__ S, int cols,
                                                   const int* __restrict__ Kc, int b0,
                                                   int rows_per_b) {
    int rowi = blockIdx.x, tid = threadIdx.x;
    u16* p = S + (size_t)rowi * cols;
    int lim = Kc ? Kc[b0 + rowi / rows_per_b] : cols;
    __shared__ float red[256];
    if (lim <= 0) { for (int j = tid; j < cols; j += 256) p[j] = 0; return; }
    float v[32];
    int nit = (lim + 255) >> 8;
    float mx = -3.4e38f;
    for (int s = 0; s < nit; ++s) {
        int j = s * 256 + tid;
        float x = (j < lim) ? bf2f(p[j]) : -3.4e38f;
        v[s] = x;
        mx = fmaxf(mx, x);
    }
    red[tid] = mx; __syncthreads();
    for (int s = 128; s > 0; s >>= 1) { if (tid < s) red[tid] = fmaxf(red[tid], red[tid + s]); __syncthreads(); }
    mx = red[0]; __syncthreads();
    float sum = 0.f;
    for (int s = 0; s < nit; ++s) {
        int j = s * 256 + tid;
        float e = (j < lim) ? expf(v[s] - mx) : 0.f;
        v[s] = e; sum += e;
    }
    red[tid] = sum; __syncthreads();
    for (int s = 128; s > 0; s >>= 1) { if (tid < s) red[tid] += red[tid + s]; __syncthreads(); }
    float inv = (red[0] > 0.f) ? 1.f / red[0] : 0.f;
    int nco = (cols + 255) >> 8;
    for (int s = 0; s < nco; ++s) {
        int j = s * 256 + tid;
        if (j < cols) p[j] = f2bf((s < nit && j < lim) ? v[s] * inv : 0.f);
    }
}

// ---------------------------------------------------------------------------
// Flash cross-attention. Q: qg (512 x QLD head-padded). KV: kvn (32768 x KVLD):
// K col = h*96+dd, V col = 768+h*96+dd (dd pads zero). Emits unnormalized
// O-partials (bh,c,128,80) fp32 + (m,l) stats (bh,c,128,2).
#define KS_LD 104
__global__ __launch_bounds__(256) void flash_ctx(
    const u16* __restrict__ qg,    // (512, QLD)
    const u16* __restrict__ kvn,   // (32768, KVLD)
    const int* __restrict__ Kc,
    float* __restrict__ Opart,     // (32,NCH,128,80)
    float* __restrict__ mlb,       // (32,NCH,128,2)
    float scale) {
    int ch = blockIdx.x, bh = blockIdx.y;
    int b = bh >> 3, h = bh & 7;
    int lim = Kc[b];
    int v0 = ch * FCH;
    int nval = min(FCH, lim - v0);
    int tid = threadIdx.x, wv = tid >> 6, lane = tid & 63;
    int fr = lane & 15, fc = lane >> 4;
    float* Op = Opart + ((size_t)bh * NCH + ch) * (128 * 80);
    float* mlp = mlb + ((size_t)bh * NCH + ch) * 256;
    if (nval <= 0) {
        for (int i = tid; i < 128 * 80; i += 256) Op[i] = 0.f;
        for (int i = tid; i < 128; i += 256) { mlp[2 * i] = -3.4e38f; mlp[2 * i + 1] = 0.f; }
        return;
    }
    __shared__ __align__(16) u16 Ks[FKT * KS_LD];   // 13.3 KB
    __shared__ __align__(16) u16 Vt[80 * 72];       // 11.3 KB
    __shared__ __align__(16) u16 Ps[4 * 32 * 72];   // 18 KB
    const u16* kbase = kvn + ((size_t)b * NVOX) * KVLD + h * DHP;
    const u16* vbase = kbase + QLD;
    // Q fragments (wave rows wv*32..wv*32+31)
    short8 qf[2][3];
    const u16* qb = qg + ((size_t)(b * NL) + wv * 32) * QLD + h * DHP;
#pragma unroll
    for (int i = 0; i < 2; ++i)
#pragma unroll
        for (int kk = 0; kk < 3; ++kk)
            qf[i][kk] = *(const short8*)(qb + (size_t)(i * 16 + fr) * QLD + kk * 32 + fc * 8);
    float m_run[2][4], l_run[2][4];
#pragma unroll
    for (int i = 0; i < 2; ++i)
#pragma unroll
        for (int r = 0; r < 4; ++r) { m_run[i][r] = -3.4e38f; l_run[i][r] = 0.f; }
    f32x4 o[2][5] = {};
    u16* Pw = Ps + wv * (32 * 72);
    int ktiles = (nval + FKT - 1) / FKT;
    for (int kt = 0; kt < ktiles; ++kt) {
        int kvox = v0 + kt * FKT;
        // stage K tile: 64 rows x 96 (LDS ld 104)
        for (int t = 0; t < 3; ++t) {
            int idx = t * 256 + tid;                 // 768 chunks of 8 u16
            int row = idx / 12, cc = idx - row * 12;
            short8 v = *(const short8*)(kbase + (size_t)(kvox + row) * KVLD + cc * 8);
            *(short8*)(Ks + row * KS_LD + cc * 8) = v;
        }
        // stage V^T tile: read V rows (vox, 80 dd), transpose into Vt (80 x 72)
        for (int t = 0; t < 3; ++t) {
            int idx = t * 256 + tid;                 // 640 chunks
            if (idx < 640) {
                int row = idx / 10, c8 = idx - row * 10;
                short8 v = *(const short8*)(vbase + (size_t)(kvox + row) * KVLD + c8 * 8);
#pragma unroll
                for (int e = 0; e < 8; ++e)
                    Vt[(c8 * 8 + e) * 72 + row] = (u16)v[e];
            }
        }
        __syncthreads();
        // S = Q K^T  (m=32 rows of this wave, n=64)
        f32x4 sc[2][4] = {};
#pragma unroll
        for (int kk = 0; kk < 3; ++kk) {
            short8 bf[4];
#pragma unroll
            for (int j = 0; j < 4; ++j)
                bf[j] = *(const short8*)(Ks + (j * 16 + fr) * KS_LD + kk * 32 + fc * 8);
#pragma unroll
            for (int i = 0; i < 2; ++i)
#pragma unroll
                for (int j = 0; j < 4; ++j)
                    sc[i][j] = __builtin_amdgcn_mfma_f32_16x16x32_bf16(qf[i][kk], bf[j], sc[i][j], 0, 0, 0);
        }
        // online softmax per row (C-layout: col=fr in frag j, row=fc*4+r in frag i)
        float alpha[2][4];
#pragma unroll
        for (int i = 0; i < 2; ++i) {
#pragma unroll
            for (int r = 0; r < 4; ++r) {
                float mt = -3.4e38f;
#pragma unroll
                for (int j = 0; j < 4; ++j) {
                    int cl = kt * FKT + j * 16 + fr;
                    float s = (cl < nval) ? sc[i][j][r] * scale : -3.4e38f;
                    sc[i][j][r] = s;
                    mt = fmaxf(mt, s);
                }
                for (int sft = 1; sft < 16; sft <<= 1) mt = fmaxf(mt, __shfl_xor(mt, sft, 16));
                float mn = fmaxf(m_run[i][r], mt);
                float al = __expf(m_run[i][r] - mn);
                m_run[i][r] = mn;
                float lt = 0.f;
#pragma unroll
                for (int j = 0; j < 4; ++j) {
                    float p = __expf(sc[i][j][r] - mn);
                    sc[i][j][r] = p;
                    lt += p;
                }
                for (int sft = 1; sft < 16; sft <<= 1) lt += __shfl_xor(lt, sft, 16);
                l_run[i][r] = l_run[i][r] * al + lt;
                alpha[i][r] = al;
            }
        }
        // P -> LDS (per-wave region), rescale O
#pragma unroll
        for (int i = 0; i < 2; ++i)
#pragma unroll
            for (int j = 0; j < 4; ++j)
#pragma unroll
                for (int r = 0; r < 4; ++r)
                    Pw[(i * 16 + fc * 4 + r) * 72 + j * 16 + fr] = f2bf(sc[i][j][r]);
#pragma unroll
        for (int i = 0; i < 2; ++i)
#pragma unroll
            for (int n = 0; n < 5; ++n)
#pragma unroll
                for (int r = 0; r < 4; ++r)
                    o[i][n][r] *= alpha[i][r];
        __syncthreads();
        // O += P @ V
#pragma unroll
        for (int kk = 0; kk < 2; ++kk) {
            short8 pf[2], vf[5];
#pragma unroll
            for (int i = 0; i < 2; ++i)
                pf[i] = *(const short8*)(Pw + (i * 16 + fr) * 72 + kk * 32 + fc * 8);
#pragma unroll
            for (int n = 0; n < 5; ++n)
                vf[n] = *(const short8*)(Vt + (n * 16 + fr) * 72 + kk * 32 + fc * 8);
#pragma unroll
            for (int i = 0; i < 2; ++i)
#pragma unroll
                for (int n = 0; n < 5; ++n)
                    o[i][n] = __builtin_amdgcn_mfma_f32_16x16x32_bf16(pf[i], vf[n], o[i][n], 0, 0, 0);
        }
        __syncthreads();
    }
#pragma unroll
    for (int i = 0; i < 2; ++i) {
#pragma unroll
        for (int n = 0; n < 5; ++n)
#pragma unroll
            for (int r = 0; r < 4; ++r) {
                int row = wv * 32 + i * 16 + fc * 4 + r;
                Op[row * 80 + n * 16 + fr] = o[i][n][r];
            }
        if (fr == 0) {
#pragma unroll
            for (int r = 0; r < 4; ++r) {
                int row = wv * 32 + i * 16 + fc * 4 + r;
                mlp[2 * row] = m_run[i][r];
                mlp[2 * row + 1] = l_run[i][r];
            }
        }
    }
}

// combine flash partials -> attn_bf (512 x INNERP bf16, pad-zeroed)
__global__ __launch_bounds__(128) void combine_ctx(const float* __restrict__ Opart,
                                                   const float* __restrict__ mlb,
                                                   u16* __restrict__ attn_bf) {
    int blk = blockIdx.x;                // bh*128 + row
    int bh = blk >> 7, row = blk & 127;
    int b = bh >> 3, h = bh & 7;
    int tid = threadIdx.x;
    float mc[NCH], lc[NCH];
    float mstar = -3.4e38f;
    for (int c = 0; c < NCH; ++c) {
        const float* mlp = mlb + ((size_t)bh * NCH + c) * 256 + 2 * row;
        mc[c] = mlp[0]; lc[c] = mlp[1];
        mstar = fmaxf(mstar, mc[c]);
    }
    float L = 0.f;
    float wc[NCH];
    for (int c = 0; c < NCH; ++c) {
        float ww = __expf(mc[c] - mstar);
        wc[c] = ww; L += ww * lc[c];
    }
    float invL = (L > 0.f) ? 1.f / L : 0.f;
    if (tid < DH) {
        float s = 0.f;
        for (int c = 0; c < NCH; ++c)
            s += Opart[(((size_t)bh * NCH + c) * 128 + row) * 80 + tid] * wc[c];
        attn_bf[((size_t)(b * 128 + row)) * INNERP + h * DH + tid] = f2bf(s * invL);
    }
    if (h == 7 && tid >= DH && tid < DH + (INNERP - INNER))
        attn_bf[((size_t)(b * 128 + row)) * INNERP + INNER + (tid - DH)] = 0;
}

// ---------------------------------------------------------------------------
// bf16 MFMA GEMM with global_load_lds staging. D = alpha * A @ B^T_layout (+bias, act).
// SWAPPED MFMA operands: lane holds 4 consecutive output COLUMNS at fixed row,
// so mode-2 stores are 8B-vectorized. Grid: x = N-tiles (inner), y = M-tiles.
// modes: 1 = f32 atomicAdd, 2 = bf16 store, 6 = fused logits->d_out permute atomicAdd.
__global__ __launch_bounds__(256) void gemm_bf16(
    const u16* __restrict__ A, const u16* __restrict__ B, void* __restrict__ Dv,
    const float* __restrict__ alphaPtr, int alphaIdx, float alphaConst,
    int M, int N, int K, int lda, int ldb, int ldd, int nh,
    ll sAo, ll sAi, ll sBo, ll sBi, ll sDo, ll sDi,
    int splitK, int mode, const float* __restrict__ bias, float biasScale, int act) {
    __shared__ __align__(16) u16 As[128 * BK];
    __shared__ __align__(16) u16 Bs[128 * BK];
    const int tid = threadIdx.x;
    int zb = blockIdx.z / splitK, kc = blockIdx.z - zb * splitK;
    int zo = zb / nh, zi = zb - zo * nh;
    const u16* Ab = A + (size_t)zo * sAo + (size_t)zi * sAi;
    const u16* Bb = B + (size_t)zo * sBo + (size_t)zi * sBi;
    const int bm = blockIdx.y * 128, bn = blockIdx.x * 128;
    int nk = K >> 5;
    int per = (nk + splitK - 1) / splitK;
    int k0 = kc * per * BK;
    int k1 = min(K, k0 + per * BK);

    const int wv = tid >> 6, lane = tid & 63;
    const int wm = (wv & 1) << 6, wn = (wv >> 1) << 6;
    const int fr = lane & 15, fc = lane >> 4;
    f32x4 acc[4][4] = {};

    const int lr = lane >> 2, lc = (lane & 3) << 3;
    const u16* ga0 = Ab + (size_t)(bm + wv * 16 + lr) * lda + k0 + lc;
    const u16* ga1 = ga0 + (size_t)64 * lda;
    const u16* gb0 = Bb + (size_t)(bn + wv * 16 + lr) * ldb + k0 + lc;
    const u16* gb1 = gb0 + (size_t)64 * ldb;
    u16* la0 = As + (wv * 16) * BK;
    u16* la1 = As + (wv * 16 + 64) * BK;
    u16* lb0 = Bs + (wv * 16) * BK;
    u16* lb1 = Bs + (wv * 16 + 64) * BK;

    for (int kb = k0; kb < k1; kb += BK) {
        gload_lds16(ga0, la0);
        gload_lds16(ga1, la1);
        gload_lds16(gb0, lb0);
        gload_lds16(gb1, lb1);
        ga0 += BK; ga1 += BK; gb0 += BK; gb1 += BK;
        __syncthreads();
        short8 af[4], bfr[4];
#pragma unroll
        for (int i = 0; i < 4; ++i)
            af[i] = *(const short8*)(As + (wm + i * 16 + fr) * BK + fc * 8);
#pragma unroll
        for (int j = 0; j < 4; ++j)
            bfr[j] = *(const short8*)(Bs + (wn + j * 16 + fr) * BK + fc * 8);
        // swapped operand order: acc[i][j] holds C^T fragment
        //   output row  gm = bm + wm + i*16 + fr
        //   output cols gn = bn + wn + j*16 + fc*4 + r  (r = 0..3 consecutive)
#pragma unroll
        for (int i = 0; i < 4; ++i)
#pragma unroll
            for (int j = 0; j < 4; ++j)
                acc[i][j] = __builtin_amdgcn_mfma_f32_16x16x32_bf16(bfr[j], af[i], acc[i][j], 0, 0, 0);
        __syncthreads();
    }
    float alpha = alphaConst * (alphaPtr ? alphaPtr[alphaIdx] : 1.f);
    if (mode == 6) {
        float* Do = (float*)Dv;
#pragma unroll
        for (int i = 0; i < 4; ++i) {
            int gm = bm + wm + i * 16 + fr;
            if (gm >= M) continue;
            int b = gm >> 7, l = gm & 127;
            int tt = l & 7, nn = l >> 3;
            size_t obase = (((size_t)(tt * BATCH + b)) * 16 + nn) * 64;
#pragma unroll
            for (int j = 0; j < 4; ++j) {
                int gn0 = bn + wn + j * 16 + fc * 4;
#pragma unroll
                for (int r = 0; r < 4; ++r) {
                    int gn = gn0 + r;
                    if (gn >= N) continue;
                    float bv = bias ? bias[gn] * biasScale : 0.f;
                    atomicAdd(&Do[obase + gn], acc[i][j][r] * alpha + bv);
                }
            }
        }
        return;
    }
    float* Db = (float*)Dv + (size_t)zo * sDo + (size_t)zi * sDi;
    u16* Du = (u16*)Dv + (size_t)zo * sDo + (size_t)zi * sDi;
    int vec4 = (mode == 2) && (((unsigned)(ldd | N | (int)(sDi & 3) | (int)(sDo & 3)) & 3u) == 0u);
#pragma unroll
    for (int i = 0; i < 4; ++i) {
        int gm = bm + wm + i * 16 + fr;
        if (gm >= M) continue;
#pragma unroll
        for (int j = 0; j < 4; ++j) {
            int gn0 = bn + wn + j * 16 + fc * 4;
            if (vec4) {
                if (gn0 >= N) continue;
                short4v pk;
#pragma unroll
                for (int r = 0; r < 4; ++r) {
                    float v = acc[i][j][r] * alpha + (bias ? bias[gn0 + r] * biasScale : 0.f);
                    if (act) v = 0.5f * v * (1.f + erff(v * 0.70710678118654752f));
                    pk[r] = (short)f2bf(v);
                }
                *(short4v*)(Du + (size_t)gm * ldd + gn0) = pk;
            } else {
#pragma unroll
                for (int r = 0; r < 4; ++r) {
                    int gn = gn0 + r;
                    if (gn >= N) continue;
                    float v = acc[i][j][r] * alpha + (bias ? bias[gn] * biasScale : 0.f);
                    if (act) v = 0.5f * v * (1.f + erff(v * 0.70710678118654752f));
                    size_t di = (size_t)gm * ldd + gn;
                    if (mode == 2) Du[di] = f2bf(v);
                    else           atomicAdd(&Db[di], v);
                }
            }
        }
    }
}

// ---------------------------------------------------------------------------
extern "C" void kernel_launch(void* const* d_in, const int* in_sizes, int n_in,
                              void* d_out, int out_size, void* d_ws, size_t ws_size,
                              hipStream_t stream) {
    const float* input    = (const float*)d_in[0];
    const float* latents  = (const float*)d_in[1];
    const float* pos_emb  = (const float*)d_in[2];
    const float* ca_g     = (const float*)d_in[3];
    const float* ca_ctx_g = (const float*)d_in[4];
    const float* ca_q     = (const float*)d_in[5];
    const float* ca_kv    = (const float*)d_in[6];
    const float* ca_ow    = (const float*)d_in[7];
    const float* ca_ob    = (const float*)d_in[8];
    const float* cf_g     = (const float*)d_in[9];
    const float* cf_w1    = (const float*)d_in[10];
    const float* cf_b1    = (const float*)d_in[11];
    const float* cf_w2    = (const float*)d_in[12];
    const float* cf_b2    = (const float*)d_in[13];
    const float* la_g     = (const float*)d_in[14];
    const float* la_q     = (const float*)d_in[15];
    const float* la_kv    = (const float*)d_in[16];
    const float* la_ow    = (const float*)d_in[17];
    const float* la_ob    = (const float*)d_in[18];
    const float* lf_g     = (const float*)d_in[19];
    const float* lf_w1    = (const float*)d_in[20];
    const float* lf_b1    = (const float*)d_in[21];
    const float* lf_w2    = (const float*)d_in[22];
    const float* lf_b2    = (const float*)d_in[23];
    const float* logits_w = (const float*)d_in[24];
    const float* logits_b = (const float*)d_in[25];
    float* out = (float*)d_out;
    (void)ws_size; (void)n_in; (void)in_sizes; (void)out_size;

    // workspace carve (~177 MB)
    char* w = (char*)d_ws;
    auto alloc = [&](size_t bytes) { void* p = (void*)w; w += (bytes + 255) & ~(size_t)255; return p; };
    int* perm        = (int*)alloc((size_t)BATCH * NVOX * 4);
    int* Kc          = (int*)alloc(64);
    unsigned char* mask = (unsigned char*)alloc((size_t)BATCH * NVOX);
    float* lat       = (float*)alloc((size_t)BATCH * NL * LD * 4);
    u16* latn_bf     = (u16*)alloc((size_t)BATCH * NL * LD * 2);
    u16* qg          = (u16*)alloc((size_t)BATCH * NL * QLD * 2);      // ctx Q, head-padded
    u16* qkvs        = (u16*)alloc((size_t)BATCH * NL * QKVLD * 2);    // self QKV, head-padded
    u16* attn_bf     = (u16*)alloc((size_t)BATCH * NL * INNERP * 2);
    u16* ffb_bf      = (u16*)alloc((size_t)BATCH * NL * FFD * 2);
    u16* vs_t        = (u16*)alloc((size_t)BATCH * HEADS * DH * NL * 2);
    alloc(64 * 1024);  // pad: B over-read slack behind vs_t
    // padded-layout weights (zero-filled once; pad rows never rewritten)
    u16* wqp_t   = (u16*)alloc((size_t)QLD * LD * 2);
    u16* wkv_t   = (u16*)alloc((size_t)KVLD * IDP * 2);
    u16* wlqkv_t = (u16*)alloc((size_t)QKVLD * LD * 2);
    size_t padw_f32 = ((size_t)QLD * LD + (size_t)KVLD * IDP + (size_t)QKVLD * LD) / 2;
    // plain transposed weights
    u16* wow_t   = (u16*)alloc((size_t)LD * INNERP * 2);
    u16* wf1_t   = (u16*)alloc((size_t)FFD * LD * 2);
    u16* wf2_t   = (u16*)alloc((size_t)LD * FFD * 2);
    u16* wlow_t  = (u16*)alloc((size_t)LD * INNERP * 2);
    u16* wlf1_t  = (u16*)alloc((size_t)FFD * LD * 2);
    u16* wlf2_t  = (u16*)alloc((size_t)LD * FFD * 2);
    u16* wlog_t  = (u16*)alloc((size_t)OC * LD * 2);
    u16* normed  = (u16*)alloc((size_t)BATCH * NVOX * IDP * 2);        // 29.4 MB
    u16* E       = (u16*)alloc((size_t)2 * 1024 * 1024);               // self scores
    u16* kvn     = (u16*)alloc((size_t)BATCH * NVOX * KVLD * 2);       // 100.7 MB
    alloc((size_t)64 * 1024);
    float* Opart = (float*)alloc((size_t)32 * NCH * 128 * 80 * 4);     // 21 MB
    float* mlb   = (float*)alloc((size_t)32 * NCH * 128 * 2 * 4);

    const float scaleS = 1.0f / sqrtf((float)DH);
    const int M4 = BATCH * NL;

    auto G = [&](const u16* A, const u16* B, void* D, const float* aP, int aI, float aC,
                 int M, int N, int K, int lda, int ldb, int ldd, int nh, int nb,
                 ll sAo, ll sAi, ll sBo, ll sBi, ll sDo, ll sDi,
                 int splitK, int mode, const float* bias = nullptr, float biasScale = 1.f,
                 int act = 0) {
        dim3 g((N + 127) / 128, (M + 127) / 128, nb * splitK);   // x = N-tiles (inner)
        hipLaunchKernelGGL(gemm_bf16, g, dim3(256), 0, stream, A, B, D, aP, aI, aC,
                           M, N, K, lda, ldb, ldd, nh, sAo, sAi, sBo, sBi, sDo, sDi,
                           splitK, mode, bias, biasScale, act);
    };

    hipLaunchKernelGGL(mask_kernel, dim3((BATCH * NVOX + 255) / 256), dim3(256), 0, stream, input, mask);
    hipLaunchKernelGGL(compact_kernel, dim3(BATCH), dim3(64), 0, stream, mask, perm, Kc);
    hipLaunchKernelGGL(lat_init, dim3((BATCH * NL * LD + 255) / 256), dim3(256), 0, stream, latents, pos_emb, lat);
    // zero the padded weight buffers once (pad rows stay zero across layers)
    hipLaunchKernelGGL(fill_kernel, dim3(((ll)padw_f32 + 255) / 256), dim3(256), 0, stream,
                       (float*)wqp_t, (ll)padw_f32, 0.f);
    hipLaunchKernelGGL(build_all, dim3(BATCH * NVOX), dim3(256), 0, stream, input, perm, Kc, normed);

    for (int d = 0; d < DEPTH; ++d) {
        // ---- all weight transposes for this layer in ONE launch ----
        TJobs J;
        int t = 0;
        auto addJob = [&](const float* s, u16* ds, int R, int C, int Rp, int fl) {
            J.src[t] = s; J.dst[t] = ds; J.R[t] = R; J.C[t] = C; J.Rp[t] = Rp; J.flag[t] = fl;
            J.tstart[t] = (t == 0) ? 0 : J.tstart[t - 1] +
                          (J.Rp[t - 1] >> 5) * ((J.C[t - 1] + 31) >> 5);
            ++t;
        };
        addJob(ca_q  + (size_t)d * LD * INNER,     wqp_t,   LD,  INNER,     LD,     1);
        addJob(ca_kv + (size_t)d * ID * 2 * INNER, wkv_t,   ID,  2 * INNER, IDP,    2);
        addJob(ca_ow + (size_t)d * INNER * LD,     wow_t,   INNER, LD,      INNERP, 0);
        addJob(cf_w1 + (size_t)d * LD * FFD,       wf1_t,   LD,  FFD,       LD,     0);
        addJob(cf_w2 + (size_t)d * FFD * LD,       wf2_t,   FFD, LD,        FFD,    0);
        addJob(la_q  + (size_t)d * LD * INNER,     wlqkv_t, LD,  INNER,     LD,     1);
        addJob(la_kv + (size_t)d * LD * 2 * INNER, wlqkv_t + (size_t)QLD * LD, LD, 2 * INNER, LD, 2);
        addJob(la_ow + (size_t)d * INNER * LD,     wlow_t,  INNER, LD,      INNERP, 0);
        addJob(lf_w1 + (size_t)d * LD * FFD,       wlf1_t,  LD,  FFD,       LD,     0);
        addJob(lf_w2 + (size_t)d * FFD * LD,       wlf2_t,  FFD, LD,        FFD,    0);
        if (d == 0) addJob(logits_w,               wlog_t,  LD,  OC,        LD,     0);
        J.njobs = t;
        J.tstart[t] = J.tstart[t - 1] + (J.Rp[t - 1] >> 5) * ((J.C[t - 1] + 31) >> 5);
        hipLaunchKernelGGL(transpose_multi, dim3(J.tstart[t]), dim3(256), 0, stream, J);

        // ---- cross attention (flash) ----
        hipLaunchKernelGGL(scale_norm_bf, dim3(M4), dim3(256), 0, stream, lat, latn_bf, ca_g, d, LD);
        G(latn_bf, wqp_t, qg, nullptr, 0, 1.f, M4, QLD, LD, LD, LD, QLD, 1, 1,
          0, 0, 0, 0, 0, 0, 1, 2);
        // KV projection all batches: 32768 x 1536, coalesced head-padded store
        G(normed, wkv_t, kvn, ca_ctx_g, d, 1.f, BATCH * NVOX, KVLD, IDP, IDP, IDP, KVLD, 1, 1,
          0, 0, 0, 0, 0, 0, 1, 2);
        hipLaunchKernelGGL(flash_ctx, dim3(NCH, 32), dim3(256), 0, stream,
                           qg, kvn, Kc, Opart, mlb, scaleS);
        hipLaunchKernelGGL(combine_ctx, dim3(32 * 128), dim3(128), 0, stream, Opart, mlb, attn_bf);
        G(attn_bf, wow_t, lat, nullptr, 0, 1.f, M4, LD, INNERP, INNERP, INNERP, LD, 1, 1,
          0, 0, 0, 0, 0, 0, 2, 1, ca_ob + (size_t)d * LD, 0.5f);

        // ---- FF (cf) ----
        hipLaunchKernelGGL(scale_norm_bf, dim3(M4), dim3(256), 0, stream, lat, latn_bf, cf_g, d, LD);
        G(latn_bf, wf1_t, ffb_bf, nullptr, 0, 1.f, M4, FFD, LD, LD, LD, FFD, 1, 1,
          0, 0, 0, 0, 0, 0, 1, 2, cf_b1 + (size_t)d * FFD, 1.f, 1);
        G(ffb_bf, wf2_t, lat, nullptr, 0, 1.f, M4, LD, FFD, FFD, FFD, LD, 1, 1,
          0, 0, 0, 0, 0, 0, 8, 1, cf_b2 + (size_t)d * LD, 0.125f);

        // ---- latent self attention ----
        hipLaunchKernelGGL(scale_norm_bf, dim3(M4), dim3(256), 0, stream, lat, latn_bf, la_g, d, LD);
        G(latn_bf, wlqkv_t, qkvs, nullptr, 0, 1.f, M4, QKVLD, LD, LD, LD, QKVLD, 1, 1,
          0, 0, 0, 0, 0, 0, 1, 2);
        hipLaunchKernelGGL(pack_vt_self, dim3((BATCH * HEADS * DH * NL + 255) / 256), dim3(256), 0, stream,
                           qkvs, vs_t);
        // S_self: A=Q section, B=K section, read in place via (b,h) strides
        G(qkvs, qkvs + QLD, E, nullptr, 0, scaleS, NL, NL, DHP, QKVLD, QKVLD, NL, 8, 32,
          (ll)NL * QKVLD, (ll)DHP, (ll)NL * QKVLD, (ll)DHP,
          (ll)HEADS * NL * NL, (ll)NL * NL, 1, 2);
        hipLaunchKernelGGL(softmax_u16, dim3(BATCH * HEADS * NL), dim3(256), 0, stream,
                           E, NL, (const int*)nullptr, 0, HEADS * NL);
        G(E, vs_t, attn_bf, nullptr, 0, 1.f, NL, DH, NL, NL, NL, INNERP, 8, 32,
          (ll)HEADS * NL * NL, (ll)NL * NL, (ll)HEADS * DH * NL, (ll)DH * NL,
          (ll)NL * INNERP, (ll)DH, 1, 2);
        G(attn_bf, wlow_t, lat, nullptr, 0, 1.f, M4, LD, INNERP, INNERP, INNERP, LD, 1, 1,
          0, 0, 0, 0, 0, 0, 2, 1, la_ob + (size_t)d * LD, 0.5f);

        // ---- FF (lf) ----
        hipLaunchKernelGGL(scale_norm_bf, dim3(M4), dim3(256), 0, stream, lat, latn_bf, lf_g, d, LD);
        G(latn_bf, wlf1_t, ffb_bf, nullptr, 0, 1.f, M4, FFD, LD, LD, LD, FFD, 1, 1,
          0, 0, 0, 0, 0, 0, 1, 2, lf_b1 + (size_t)d * FFD, 1.f, 1);
        G(ffb_bf, wlf2_t, lat, nullptr, 0, 1.f, M4, LD, FFD, FFD, FFD, LD, 1, 1,
          0, 0, 0, 0, 0, 0, 8, 1, lf_b2 + (size_t)d * LD, 0.125f);
    }

    // logits fused with output permute
    hipLaunchKernelGGL(conv_bf, dim3((M4 * LD + 255) / 256), dim3(256), 0, stream, lat, latn_bf, M4 * LD);
    hipLaunchKernelGGL(fill_kernel, dim3((TBINS * BATCH * 16 * OC + 255) / 256), dim3(256), 0, stream,
                       out, (ll)TBINS * BATCH * 16 * OC, 0.f);
    G(latn_bf, wlog_t, out, nullptr, 0, 1.f, M4, OC, LD, LD, LD, 0, 1, 1,
      0, 0, 0, 0, 0, 0, 4, 6, logits_b, 0.25f);
}